// Round 1
// baseline (283.342 us; speedup 1.0000x reference)
//
#include <hip/hip_runtime.h>
#include <math.h>

#define BATCH 131072
#define DIM 256
#define NK 5
#define BT 3.0f
#define NBLK 1024    // 4 blocks/CU x 256 CU, exactly co-resident
#define NTHR 512     // 8 waves/block -> 32 waves/CU
#define ITERS 8      // BATCH / (NBLK * 8 waves * 2 rows)

__global__ __launch_bounds__(NTHR, 8) void rqs_kernel(
    const float* __restrict__ u,
    const float* __restrict__ wp,
    const float* __restrict__ hp,
    const float* __restrict__ dp,
    float* __restrict__ x_out,
    float* __restrict__ ld_out)
{
    // De-interleaved per-(bin,dim) records, 16 B/lane stride -> conflict-free
    // ds_read_b128 (interleaved 32 B stride was a 2-way bank conflict, 6.4M cycles).
    //   tabA[k*DIM+dim] = (xk, 1/width, s = dk+dk1-2*delta, delta)
    //   tabB[k*DIM+dim] = (p = h*(delta-dk), q = h*dk, yk, rb = 2*(delta-dk))
    // Math:  theta = (uc-xk)*iw
    //        denom = fma(fma(-s,th,s),th,delta)            (= delta + s*th*(1-th))
    //        num   = th*fma(p,th,q)                        (= h*(delta*th^2 + dk*th(1-th)))
    //        ldq   = fma(fma(s,th,rb),th,dk)               (= dk1*th^2+2delta*th(1-th)+dk*(1-th)^2)
    //        ld    = log(ldq * delta^2 * invd^2)
    // At th==0 (low tail, dk=1) and th==1 (high tail, dk1=1) the log argument is 1 -> ld == 0,
    // so no 'inside' select needed on ld.
    __shared__ float4 tabA[NK * DIM];   // 20480 B
    __shared__ float4 tabB[NK * DIM];   // 20480 B ; total 40960 -> 4 blocks = 160 KiB/CU
    const int tid = threadIdx.x;

    if (tid < DIM) {
        const int dm = tid;
        float v[NK], wid[NK], xpos[NK], hei[NK], ypos[NK], dv[NK + 1];
        float mx, sum, scale, c;

        mx = -1e30f;
        #pragma unroll
        for (int k = 0; k < NK; k++) { v[k] = wp[dm * NK + k]; mx = fmaxf(mx, v[k]); }
        sum = 0.f;
        #pragma unroll
        for (int k = 0; k < NK; k++) { v[k] = expf(v[k] - mx); sum += v[k]; }
        scale = 6.0f / sum;
        c = -BT;
        #pragma unroll
        for (int k = 0; k < NK; k++) { wid[k] = v[k] * scale; xpos[k] = c; c += wid[k]; }

        mx = -1e30f;
        #pragma unroll
        for (int k = 0; k < NK; k++) { v[k] = hp[dm * NK + k]; mx = fmaxf(mx, v[k]); }
        sum = 0.f;
        #pragma unroll
        for (int k = 0; k < NK; k++) { v[k] = expf(v[k] - mx); sum += v[k]; }
        scale = 6.0f / sum;
        c = -BT;
        #pragma unroll
        for (int k = 0; k < NK; k++) { hei[k] = v[k] * scale; ypos[k] = c; c += hei[k]; }

        dv[0] = 1.0f; dv[NK] = 1.0f;
        #pragma unroll
        for (int k = 0; k < 4; k++) dv[1 + k] = log1pf(expf(dp[dm * 4 + k]));

        #pragma unroll
        for (int k = 0; k < NK; k++) {
            float iw  = 1.0f / wid[k];
            float dlt = hei[k] * iw;
            float dk  = dv[k], dk1 = dv[k + 1];
            tabA[k * DIM + dm] = make_float4(xpos[k], iw, dk + dk1 - 2.0f * dlt, dlt);
            tabB[k * DIM + dm] = make_float4(hei[k] * (dlt - dk), hei[k] * dk,
                                             ypos[k], 2.0f * (dlt - dk));
        }
    }
    __syncthreads();

    const int lane = tid & 63;
    const int wv   = tid >> 6;

    // thread owns dims lane, lane+64, lane+128, lane+192; preload interior x-knots
    float kn[4][4];
    #pragma unroll
    for (int j = 0; j < 4; j++)
        #pragma unroll
        for (int i = 0; i < 4; i++)
            kn[j][i] = tabA[(i + 1) * DIM + lane + 64 * j].x;

    const int g = (blockIdx.x << 3) | wv;   // global wave id, 0..8191

    // software prefetch of iteration 0's u values
    float uin[2][4];
    {
        const float* up = u + ((size_t)(g << 1)) * DIM + lane;
        #pragma unroll
        for (int rr = 0; rr < 2; rr++)
            #pragma unroll
            for (int j = 0; j < 4; j++)
                uin[rr][j] = up[rr * DIM + 64 * j];
    }

    for (int it = 0; it < ITERS; it++) {
        const int r0 = (it << 14) | (g << 1);   // 16384 contiguous rows per sweep

        // prefetch NEXT iteration's u: issued a full iteration ahead of use
        float unx[2][4];
        if (it + 1 < ITERS) {
            const float* up = u + ((size_t)(r0 + 16384)) * DIM + lane;
            #pragma unroll
            for (int rr = 0; rr < 2; rr++)
                #pragma unroll
                for (int j = 0; j < 4; j++)
                    unx[rr][j] = up[rr * DIM + 64 * j];
        }

        float ldacc0 = 0.f, ldacc1 = 0.f;

        #pragma unroll
        for (int rr = 0; rr < 2; rr++) {
            // phase 1: all bin indices for this row (register-only)
            float uc[4];
            int   off[4];
            #pragma unroll
            for (int j = 0; j < 4; j++) {
                float uval = uin[rr][j];
                float c = fminf(fmaxf(uval, -BT), BT);
                int idx = (int)(c >= kn[j][0]) + (int)(c >= kn[j][1])
                        + (int)(c >= kn[j][2]) + (int)(c >= kn[j][3]);
                uc[j]  = c;
                off[j] = (idx << 8) + lane + (j << 6);
            }
            // phase 2: issue all 8 conflict-free ds_read_b128 as a batch
            float4 A[4], Bv[4];
            #pragma unroll
            for (int j = 0; j < 4; j++) { A[j] = tabA[off[j]]; Bv[j] = tabB[off[j]]; }

            // phase 3: math
            float xo[4];
            float lsum = 0.f;
            #pragma unroll
            for (int j = 0; j < 4; j++) {
                float xk = A[j].x,  iw = A[j].y,  s  = A[j].z,  dlt = A[j].w;
                float p  = Bv[j].x, q  = Bv[j].y, yk = Bv[j].z, rb  = Bv[j].w;

                float th    = (uc[j] - xk) * iw;
                float dk    = fmaf(-0.5f, rb, dlt);
                float r2    = dlt * dlt;
                float denom = fmaf(fmaf(-s, th, s), th, dlt);
                float invd  = __builtin_amdgcn_rcpf(denom);
                float num   = th * fmaf(p, th, q);
                float x_in  = fmaf(num, invd, yk);
                float ldq   = fmaf(fmaf(s, th, rb), th, dk);
                float ld    = __logf(ldq * r2 * invd * invd);

                xo[j] = (uc[j] == uin[rr][j]) ? x_in : uin[rr][j];
                lsum += ld;          // == 0 (to fp eps) for tail elements
            }
            if (rr == 0) ldacc0 = lsum; else ldacc1 = lsum;

            float* xp = x_out + (size_t)(r0 + rr) * DIM + lane;
            #pragma unroll
            for (int j = 0; j < 4; j++)
                __builtin_nontemporal_store(xo[j], xp + 64 * j);
        }

        #pragma unroll
        for (int sh = 32; sh > 0; sh >>= 1) {
            ldacc0 += __shfl_down(ldacc0, sh, 64);
            ldacc1 += __shfl_down(ldacc1, sh, 64);
        }
        if (lane == 0) {
            __builtin_nontemporal_store(ldacc0, ld_out + r0);
            __builtin_nontemporal_store(ldacc1, ld_out + r0 + 1);
        }

        if (it + 1 < ITERS) {
            #pragma unroll
            for (int rr = 0; rr < 2; rr++)
                #pragma unroll
                for (int j = 0; j < 4; j++)
                    uin[rr][j] = unx[rr][j];
        }
    }
}

extern "C" void kernel_launch(void* const* d_in, const int* in_sizes, int n_in,
                              void* d_out, int out_size, void* d_ws, size_t ws_size,
                              hipStream_t stream) {
    const float* u  = (const float*)d_in[0];
    const float* w  = (const float*)d_in[1];
    const float* h  = (const float*)d_in[2];
    const float* dd = (const float*)d_in[3];
    float* x  = (float*)d_out;
    float* ld = x + (size_t)BATCH * DIM;
    rqs_kernel<<<NBLK, NTHR, 0, stream>>>(u, w, h, dd, x, ld);
}